// Round 1
// baseline (1665.916 us; speedup 1.0000x reference)
//
#include <hip/hip_runtime.h>

#define NN 50000
#define NE 1600000
#define DIM 128

// ---------------- CSR build ----------------

__global__ void deg_count(const int* __restrict__ dst, unsigned* __restrict__ cnt, int E) {
    int e = blockIdx.x * blockDim.x + threadIdx.x;
    if (e < E) atomicAdd(&cnt[dst[e]], 1u);
}

// single-block exclusive scan over N counts -> offsets, also inv_deg
__global__ __launch_bounds__(1024) void scan_offsets(const unsigned* __restrict__ cnt,
                                                     unsigned* __restrict__ off,
                                                     float* __restrict__ inv_deg, int N) {
    __shared__ unsigned tmp[1024];
    __shared__ unsigned carry;
    if (threadIdx.x == 0) carry = 0u;
    __syncthreads();
    for (int base = 0; base < N; base += 1024) {
        int i = base + threadIdx.x;
        unsigned v = (i < N) ? cnt[i] : 0u;
        tmp[threadIdx.x] = v;
        __syncthreads();
        for (int s = 1; s < 1024; s <<= 1) {
            unsigned t = (threadIdx.x >= (unsigned)s) ? tmp[threadIdx.x - s] : 0u;
            __syncthreads();
            tmp[threadIdx.x] += t;
            __syncthreads();
        }
        unsigned incl = tmp[threadIdx.x];
        unsigned c = carry;
        if (i < N) {
            off[i] = c + incl - v;             // exclusive
            inv_deg[i] = v ? 1.0f / (float)v : 0.0f;
        }
        __syncthreads();
        if (threadIdx.x == 1023) carry = c + tmp[1023];
        __syncthreads();
    }
    if (threadIdx.x == 0) off[N] = carry;
}

__global__ void fill_perm(const int* __restrict__ dst, unsigned* __restrict__ cursor,
                          const unsigned* __restrict__ off, unsigned* __restrict__ perm, int E) {
    int e = blockIdx.x * blockDim.x + threadIdx.x;
    if (e < E) {
        int d = dst[e];
        unsigned p = atomicAdd(&cursor[d], 1u);
        perm[off[d] + p] = (unsigned)e;
    }
}

// ---------------- aggregation: one block (128 thr) per dst node ----------------

__global__ __launch_bounds__(128) void aggregate(
    const float* __restrict__ h, const float* __restrict__ ew,
    const int* __restrict__ src, const unsigned* __restrict__ perm,
    const unsigned* __restrict__ off, const float* __restrict__ inv_deg,
    float* __restrict__ agg) {
    const int v = blockIdx.x;
    const int tid = threadIdx.x;
    __shared__ int   s_src[128];
    __shared__ float s_w[128];
    const unsigned s0 = off[v], s1 = off[v + 1];
    float acc = 0.0f;
    for (unsigned base = s0; base < s1; base += 128u) {
        int cnt = (int)min(128u, s1 - base);
        if (tid < cnt) {
            unsigned e = perm[base + tid];
            s_src[tid] = src[e];
            s_w[tid]   = ew[e];
        }
        __syncthreads();
        #pragma unroll 4
        for (int j = 0; j < cnt; ++j) {
            acc += h[(size_t)s_src[j] * DIM + tid] * s_w[j];
        }
        __syncthreads();
    }
    agg[(size_t)v * DIM + tid] = acc * inv_deg[v];
}

// ---------------- dense layer: relu([agg,h] @ W.T + b) ----------------
// 32-node tile in LDS (padded), 256 threads = 32 nodes x 8 out-groups.
// In-place safe for out==h (rows staged to LDS before write).

template <int OUT>
__global__ __launch_bounds__(256) void gemm_layer(
    const float* __restrict__ agg, const float* __restrict__ h,
    const float* __restrict__ W, const float* __restrict__ b,
    float* __restrict__ out, int N) {
    constexpr int OG = OUT / 8;
    const int tile = blockIdx.x * 32;
    const int t  = threadIdx.x;
    const int tx = t & 31;   // node within tile
    const int ty = t >> 5;   // 0..7 out-group
    __shared__ float x[32][257];

    for (int idx = t; idx < 32 * 256; idx += 256) {
        int n = idx >> 8;
        int k = idx & 255;
        int v = tile + n;
        float val = 0.0f;
        if (v < N) val = (k < 128) ? agg[(size_t)v * 128 + k]
                                   : h[(size_t)v * 128 + (k - 128)];
        x[n][k] = val;
    }
    __syncthreads();

    float acc[OG];
    #pragma unroll
    for (int i = 0; i < OG; ++i) acc[i] = b[ty + 8 * i];

    for (int k = 0; k < 256; ++k) {
        float xv = x[tx][k];
        #pragma unroll
        for (int i = 0; i < OG; ++i) {
            acc[i] = fmaf(xv, W[(size_t)(ty + 8 * i) * 256 + k], acc[i]);
        }
    }

    int v = tile + tx;
    if (v < N) {
        #pragma unroll
        for (int i = 0; i < OG; ++i) {
            out[(size_t)v * OUT + ty + 8 * i] = fmaxf(acc[i], 0.0f);
        }
    }
}

// ---------------- launch ----------------

extern "C" void kernel_launch(void* const* d_in, const int* in_sizes, int n_in,
                              void* d_out, int out_size, void* d_ws, size_t ws_size,
                              hipStream_t stream) {
    const float* n_feat = (const float*)d_in[0];
    const float* ew     = (const float*)d_in[1];
    const int*   src    = (const int*)d_in[2];
    const int*   dst    = (const int*)d_in[3];
    const float* W1 = (const float*)d_in[4];
    const float* b1 = (const float*)d_in[5];
    const float* W2 = (const float*)d_in[6];
    const float* b2 = (const float*)d_in[7];
    const float* W3 = (const float*)d_in[8];
    const float* b3 = (const float*)d_in[9];

    const int N = NN, E = NE;

    // workspace carve-up (aligned to 256 B)
    uint8_t* w = (uint8_t*)d_ws;
    size_t o = 0;
    auto carve = [&](size_t bytes) { uint8_t* p = w + o; o += (bytes + 255) & ~(size_t)255; return p; };
    unsigned* cnt    = (unsigned*)carve((size_t)N * 4);        // counts, then reused as fill cursor
    unsigned* off    = (unsigned*)carve((size_t)(N + 1) * 4);
    float*    invdeg = (float*)   carve((size_t)N * 4);
    unsigned* perm   = (unsigned*)carve((size_t)E * 4);
    float*    AGG    = (float*)   carve((size_t)N * DIM * 4);
    float*    H      = (float*)   carve((size_t)N * DIM * 4);

    float* OUT = (float*)d_out;

    // --- CSR build ---
    hipMemsetAsync(cnt, 0, (size_t)N * 4, stream);
    deg_count<<<(E + 255) / 256, 256, 0, stream>>>(dst, cnt, E);
    scan_offsets<<<1, 1024, 0, stream>>>(cnt, off, invdeg, N);
    hipMemsetAsync(cnt, 0, (size_t)N * 4, stream);
    fill_perm<<<(E + 255) / 256, 256, 0, stream>>>(dst, cnt, off, perm, E);

    const int gemm_grid = (N + 31) / 32;

    // --- layer 1 ---
    aggregate<<<N, 128, 0, stream>>>(n_feat, ew, src, perm, off, invdeg, AGG);
    gemm_layer<128><<<gemm_grid, 256, 0, stream>>>(AGG, n_feat, W1, b1, H, N);

    // --- layer 2 (in-place on H) ---
    aggregate<<<N, 128, 0, stream>>>(H, ew, src, perm, off, invdeg, AGG);
    gemm_layer<128><<<gemm_grid, 256, 0, stream>>>(AGG, H, W2, b2, H, N);

    // --- layer 3 ---
    aggregate<<<N, 128, 0, stream>>>(H, ew, src, perm, off, invdeg, AGG);
    gemm_layer<64><<<gemm_grid, 256, 0, stream>>>(AGG, H, W3, b3, OUT, N);
}

// Round 2
// 850.097 us; speedup vs baseline: 1.9597x; 1.9597x over previous
//
#include <hip/hip_runtime.h>

#define NN 50000
#define NE 1600000
#define DIM 128

// ---------------- CSR build ----------------

__global__ void deg_count(const int* __restrict__ dst, unsigned* __restrict__ cnt, int E) {
    int e = blockIdx.x * blockDim.x + threadIdx.x;
    if (e < E) atomicAdd(&cnt[dst[e]], 1u);
}

// single-block exclusive scan over N counts -> offsets, also inv_deg
// wave-shuffle scan: 3 barriers per 1024-chunk instead of ~20
__global__ __launch_bounds__(1024) void scan_offsets(const unsigned* __restrict__ cnt,
                                                     unsigned* __restrict__ off,
                                                     float* __restrict__ inv_deg, int N) {
    __shared__ unsigned wsum[16];
    __shared__ unsigned carry_s;
    const int lane = threadIdx.x & 63;
    const int wid  = threadIdx.x >> 6;
    if (threadIdx.x == 0) carry_s = 0u;
    __syncthreads();
    for (int base = 0; base < N; base += 1024) {
        int i = base + threadIdx.x;
        unsigned v = (i < N) ? cnt[i] : 0u;
        // inclusive scan within wave (64 lanes)
        unsigned x = v;
        #pragma unroll
        for (int s = 1; s < 64; s <<= 1) {
            unsigned t = __shfl_up(x, s, 64);
            if (lane >= s) x += t;
        }
        if (lane == 63) wsum[wid] = x;
        __syncthreads();
        if (wid == 0 && lane < 16) {
            unsigned y = wsum[lane];
            #pragma unroll
            for (int s = 1; s < 16; s <<= 1) {
                unsigned t = __shfl_up(y, s, 64);
                if (lane >= s) y += t;
            }
            wsum[lane] = y;   // inclusive wave-prefix
        }
        __syncthreads();
        unsigned wpre = (wid > 0) ? wsum[wid - 1] : 0u;
        unsigned incl = x + wpre;
        unsigned c = carry_s;
        if (i < N) {
            off[i] = c + incl - v;               // exclusive
            inv_deg[i] = v ? 1.0f / (float)v : 0.0f;
        }
        __syncthreads();
        if (threadIdx.x == 1023) carry_s = c + incl;
        __syncthreads();
    }
    if (threadIdx.x == 0) off[N] = carry_s;
}

__global__ void fill_perm(const int* __restrict__ dst, unsigned* __restrict__ cursor,
                          const unsigned* __restrict__ off, unsigned* __restrict__ perm, int E) {
    int e = blockIdx.x * blockDim.x + threadIdx.x;
    if (e < E) {
        int d = dst[e];
        unsigned p = atomicAdd(&cursor[d], 1u);
        perm[off[d] + p] = (unsigned)e;
    }
}

// ---------------- aggregation: one block (128 thr) per dst node ----------------

__global__ __launch_bounds__(128) void aggregate(
    const float* __restrict__ h, const float* __restrict__ ew,
    const int* __restrict__ src, const unsigned* __restrict__ perm,
    const unsigned* __restrict__ off, const float* __restrict__ inv_deg,
    float* __restrict__ agg) {
    const int v = blockIdx.x;
    const int tid = threadIdx.x;
    __shared__ int   s_src[128];
    __shared__ float s_w[128];
    const unsigned s0 = off[v], s1 = off[v + 1];
    float acc = 0.0f;
    for (unsigned base = s0; base < s1; base += 128u) {
        int cnt = (int)min(128u, s1 - base);
        if (tid < cnt) {
            unsigned e = perm[base + tid];
            s_src[tid] = src[e];
            s_w[tid]   = ew[e];
        }
        __syncthreads();
        #pragma unroll 4
        for (int j = 0; j < cnt; ++j) {
            acc += h[(size_t)s_src[j] * DIM + tid] * s_w[j];
        }
        __syncthreads();
    }
    agg[(size_t)v * DIM + tid] = acc * inv_deg[v];
}

// ---------------- dense layer: relu([agg,h] @ W.T + b) ----------------
// 64-node x OUT tile per 256-thread block. K staged 32 wide in LDS for X and W.
// Each thread: 4 nodes x OPT outs register tile, float4 LDS reads.
// In-place safe for out==h: block reads only its own 64 rows, all reads
// complete (barrier) before the epilogue stores.

template <int OUT>
__global__ __launch_bounds__(256) void gemm_layer(
    const float* __restrict__ agg, const float* __restrict__ h,
    const float* __restrict__ W, const float* __restrict__ b,
    float* __restrict__ out, int N) {
    constexpr int OPT = OUT / 16;      // outs per thread: 8 (OUT=128) or 4 (OUT=64)
    const int tile = blockIdx.x * 64;
    const int t  = threadIdx.x;
    const int tx = t & 15;             // out group: outs [tx*OPT, tx*OPT+OPT)
    const int ty = t >> 4;             // node group: nodes [ty*4, ty*4+4)
    __shared__ float Xs[32][68];
    __shared__ float Ws[32][OUT + 4];

    float acc[4][OPT];
    #pragma unroll
    for (int j = 0; j < 4; ++j)
        #pragma unroll
        for (int i = 0; i < OPT; ++i) acc[j][i] = 0.0f;

    for (int k0 = 0; k0 < 256; k0 += 32) {
        // stage X tile: 64 nodes x 32 k   (first 128 k from agg, next 128 from h)
        {
            const int k  = t & 31;
            const int n0 = t >> 5;               // 0..7
            const float* __restrict__ srcp = (k0 < 128) ? agg : h;
            const int kk = (k0 & 127) + k;
            #pragma unroll
            for (int r = 0; r < 8; ++r) {
                int n = n0 + r * 8;
                int v = tile + n;
                Xs[k][n] = (v < N) ? srcp[(size_t)v * 128 + kk] : 0.0f;
            }
        }
        // stage W tile: OUT x 32
        {
            const int k  = t & 31;
            const int o0 = t >> 5;               // 0..7
            #pragma unroll
            for (int r = 0; r < OUT / 8; ++r) {
                int o = o0 + r * 8;
                Ws[k][o] = W[(size_t)o * 256 + k0 + k];
            }
        }
        __syncthreads();

        #pragma unroll
        for (int kk = 0; kk < 32; ++kk) {
            float4 x4 = *(const float4*)&Xs[kk][ty * 4];
            float wf[OPT];
            #pragma unroll
            for (int i = 0; i < OPT; i += 4) {
                float4 w4 = *(const float4*)&Ws[kk][tx * OPT + i];
                wf[i] = w4.x; wf[i+1] = w4.y; wf[i+2] = w4.z; wf[i+3] = w4.w;
            }
            float xf[4] = {x4.x, x4.y, x4.z, x4.w};
            #pragma unroll
            for (int j = 0; j < 4; ++j)
                #pragma unroll
                for (int i = 0; i < OPT; ++i)
                    acc[j][i] = fmaf(xf[j], wf[i], acc[j][i]);
        }
        __syncthreads();
    }

    // epilogue: bias + relu + store (float4)
    #pragma unroll
    for (int j = 0; j < 4; ++j) {
        int v = tile + ty * 4 + j;
        if (v < N) {
            #pragma unroll
            for (int i = 0; i < OPT; i += 4) {
                float4 r;
                r.x = fmaxf(acc[j][i + 0] + b[tx * OPT + i + 0], 0.0f);
                r.y = fmaxf(acc[j][i + 1] + b[tx * OPT + i + 1], 0.0f);
                r.z = fmaxf(acc[j][i + 2] + b[tx * OPT + i + 2], 0.0f);
                r.w = fmaxf(acc[j][i + 3] + b[tx * OPT + i + 3], 0.0f);
                *(float4*)&out[(size_t)v * OUT + tx * OPT + i] = r;
            }
        }
    }
}

// ---------------- launch ----------------

extern "C" void kernel_launch(void* const* d_in, const int* in_sizes, int n_in,
                              void* d_out, int out_size, void* d_ws, size_t ws_size,
                              hipStream_t stream) {
    const float* n_feat = (const float*)d_in[0];
    const float* ew     = (const float*)d_in[1];
    const int*   src    = (const int*)d_in[2];
    const int*   dst    = (const int*)d_in[3];
    const float* W1 = (const float*)d_in[4];
    const float* b1 = (const float*)d_in[5];
    const float* W2 = (const float*)d_in[6];
    const float* b2 = (const float*)d_in[7];
    const float* W3 = (const float*)d_in[8];
    const float* b3 = (const float*)d_in[9];

    const int N = NN, E = NE;

    // workspace carve-up (aligned to 256 B)
    uint8_t* w = (uint8_t*)d_ws;
    size_t o = 0;
    auto carve = [&](size_t bytes) { uint8_t* p = w + o; o += (bytes + 255) & ~(size_t)255; return p; };
    unsigned* cnt    = (unsigned*)carve((size_t)N * 4);        // counts, then reused as fill cursor
    unsigned* off    = (unsigned*)carve((size_t)(N + 1) * 4);
    float*    invdeg = (float*)   carve((size_t)N * 4);
    unsigned* perm   = (unsigned*)carve((size_t)E * 4);
    float*    AGG    = (float*)   carve((size_t)N * DIM * 4);
    float*    H      = (float*)   carve((size_t)N * DIM * 4);

    float* OUT = (float*)d_out;

    // --- CSR build ---
    hipMemsetAsync(cnt, 0, (size_t)N * 4, stream);
    deg_count<<<(E + 255) / 256, 256, 0, stream>>>(dst, cnt, E);
    scan_offsets<<<1, 1024, 0, stream>>>(cnt, off, invdeg, N);
    hipMemsetAsync(cnt, 0, (size_t)N * 4, stream);
    fill_perm<<<(E + 255) / 256, 256, 0, stream>>>(dst, cnt, off, perm, E);

    const int gemm_grid = (N + 63) / 64;

    // --- layer 1 ---
    aggregate<<<N, 128, 0, stream>>>(n_feat, ew, src, perm, off, invdeg, AGG);
    gemm_layer<128><<<gemm_grid, 256, 0, stream>>>(AGG, n_feat, W1, b1, H, N);

    // --- layer 2 (in-place on H) ---
    aggregate<<<N, 128, 0, stream>>>(H, ew, src, perm, off, invdeg, AGG);
    gemm_layer<128><<<gemm_grid, 256, 0, stream>>>(AGG, H, W2, b2, H, N);

    // --- layer 3 ---
    aggregate<<<N, 128, 0, stream>>>(H, ew, src, perm, off, invdeg, AGG);
    gemm_layer<64><<<gemm_grid, 256, 0, stream>>>(AGG, H, W3, b3, OUT, N);
}

// Round 3
// 621.641 us; speedup vs baseline: 2.6799x; 1.3675x over previous
//
#include <hip/hip_runtime.h>

#define NN 50000
#define NE 1600000

// ---------------- helpers ----------------

__device__ __forceinline__ unsigned pack2_bf16(float x, float y) {
    unsigned ux = __float_as_uint(x), uy = __float_as_uint(y);
    ux = (ux + 0x7fffu + ((ux >> 16) & 1u)) >> 16;          // RTNE
    uy = (uy + 0x7fffu + ((uy >> 16) & 1u)) >> 16;
    return (uy << 16) | (ux & 0xffffu);
}

// ---------------- CSR build ----------------

__global__ void deg_count(const int* __restrict__ dst, unsigned* __restrict__ cnt, int E) {
    int e = blockIdx.x * blockDim.x + threadIdx.x;
    if (e < E) atomicAdd(&cnt[dst[e]], 1u);
}

__global__ __launch_bounds__(1024) void scan_offsets(const unsigned* __restrict__ cnt,
                                                     unsigned* __restrict__ off,
                                                     float* __restrict__ inv_deg, int N) {
    __shared__ unsigned wsum[16];
    __shared__ unsigned carry_s;
    const int lane = threadIdx.x & 63;
    const int wid  = threadIdx.x >> 6;
    if (threadIdx.x == 0) carry_s = 0u;
    __syncthreads();
    for (int base = 0; base < N; base += 1024) {
        int i = base + threadIdx.x;
        unsigned v = (i < N) ? cnt[i] : 0u;
        unsigned x = v;
        #pragma unroll
        for (int s = 1; s < 64; s <<= 1) {
            unsigned t = __shfl_up(x, s, 64);
            if (lane >= s) x += t;
        }
        if (lane == 63) wsum[wid] = x;
        __syncthreads();
        if (wid == 0 && lane < 16) {
            unsigned y = wsum[lane];
            #pragma unroll
            for (int s = 1; s < 16; s <<= 1) {
                unsigned t = __shfl_up(y, s, 64);
                if (lane >= s) y += t;
            }
            wsum[lane] = y;
        }
        __syncthreads();
        unsigned wpre = (wid > 0) ? wsum[wid - 1] : 0u;
        unsigned incl = x + wpre;
        unsigned c = carry_s;
        if (i < N) {
            off[i] = c + incl - v;
            inv_deg[i] = v ? 1.0f / (float)v : 0.0f;
        }
        __syncthreads();
        if (threadIdx.x == 1023) carry_s = c + incl;
        __syncthreads();
    }
    if (threadIdx.x == 0) off[N] = carry_s;
}

// write dst-sorted packed edge stream: (w_bits<<32 | src)
__global__ void fill_edges(const int* __restrict__ dst, const int* __restrict__ src,
                           const float* __restrict__ ew,
                           unsigned* __restrict__ cursor, const unsigned* __restrict__ off,
                           unsigned long long* __restrict__ edges, int E) {
    int e = blockIdx.x * blockDim.x + threadIdx.x;
    if (e < E) {
        int d = dst[e];
        unsigned p = atomicAdd(&cursor[d], 1u);
        unsigned long long packed =
            ((unsigned long long)__float_as_uint(ew[e]) << 32) | (unsigned)(src[e]);
        edges[off[d] + p] = packed;
    }
}

// ---------------- pack f32 [N][128] -> bf16x2 u32 [N][64] ----------------

__global__ void pack_rows(const float* __restrict__ in, unsigned* __restrict__ out, int npairs) {
    int i = blockIdx.x * blockDim.x + threadIdx.x;
    if (i < npairs) {
        float2 v = *(const float2*)&in[(size_t)i * 2];
        out[i] = pack2_bf16(v.x, v.y);
    }
}

// ---------------- aggregation (128 dims, bf16 gather), wave per node ----------------

__global__ __launch_bounds__(256) void aggregate_b(
    const unsigned* __restrict__ h2,                 // [N][64] bf16x2
    const unsigned long long* __restrict__ edges,    // [E] dst-sorted (w<<32|src)
    const unsigned* __restrict__ off, const float* __restrict__ invdeg,
    float* __restrict__ agg)                          // [N][128] f32
{
    const int node = blockIdx.x * 4 + (threadIdx.x >> 6);   // 12500*4 = 50000 exact
    const int lane = threadIdx.x & 63;
    const unsigned s0 = off[node], s1 = off[node + 1];
    float a0 = 0.f, a1 = 0.f;
    for (unsigned base = s0; base < s1; base += 64u) {
        const int cnt = (int)min(64u, s1 - base);
        unsigned long long ed = 0;
        if (lane < cnt) ed = edges[base + lane];
        int e_src = (int)(unsigned)ed;
        int e_wb  = (int)(unsigned)(ed >> 32);
        #pragma unroll 4
        for (int j = 0; j < cnt; ++j) {
            int sj = __builtin_amdgcn_readlane(e_src, j);     // uniform j -> SGPR
            int wb = __builtin_amdgcn_readlane(e_wb, j);
            float wj = __uint_as_float((unsigned)wb);
            unsigned p = h2[(size_t)(unsigned)sj * 64 + lane];
            a0 = fmaf(__uint_as_float(p << 16), wj, a0);
            a1 = fmaf(__uint_as_float(p & 0xffff0000u), wj, a1);
        }
    }
    const float s = invdeg[node];
    float2 r = make_float2(a0 * s, a1 * s);
    *(float2*)&agg[(size_t)node * 128 + lane * 2] = r;
}

// ---------------- layer-3 aggregation (64 dims) + add q + relu, half-wave per node ----

__global__ __launch_bounds__(256) void aggregate64_fused(
    const unsigned* __restrict__ p2,                 // [N][32] bf16x2
    const unsigned long long* __restrict__ edges,
    const unsigned* __restrict__ off, const float* __restrict__ invdeg,
    const float* __restrict__ q,                      // [N][64]
    float* __restrict__ out)                          // [N][64]
{
    const int node = blockIdx.x * 8 + (threadIdx.x >> 5);   // 6250*8 = 50000 exact
    const int l = threadIdx.x & 31;
    const unsigned s0 = off[node], s1 = off[node + 1];
    float a0 = 0.f, a1 = 0.f;
    for (unsigned base = s0; base < s1; base += 32u) {
        const int cnt = (int)min(32u, s1 - base);
        unsigned long long ed = 0;
        if (l < cnt) ed = edges[base + l];
        int e_src = (int)(unsigned)ed;
        int e_wb  = (int)(unsigned)(ed >> 32);
        #pragma unroll 4
        for (int j = 0; j < cnt; ++j) {
            int sj = __shfl(e_src, j, 32);                  // j divergent across halves
            float wj = __uint_as_float((unsigned)__shfl(e_wb, j, 32));
            unsigned p = p2[(size_t)(unsigned)sj * 32 + l];
            a0 = fmaf(__uint_as_float(p << 16), wj, a0);
            a1 = fmaf(__uint_as_float(p & 0xffff0000u), wj, a1);
        }
    }
    const float s = invdeg[node];
    float2 qv = *(const float2*)&q[(size_t)node * 64 + l * 2];
    float2 r;
    r.x = fmaxf(a0 * s + qv.x, 0.f);
    r.y = fmaxf(a1 * s + qv.y, 0.f);
    *(float2*)&out[(size_t)node * 64 + l * 2] = r;
}

// ---------------- dense layers ----------------
// MODE 0: z = relu([agg|h] @ W.T + b), K=256, OUT=128; writes f32 + packed bf16
// MODE 1: p = h @ W3[:, :128].T (no bias/relu, packed bf16, outs 0-63)
//         q = h @ W3[:, 128:].T + b3 (f32, no relu, outs 64-127)
// 128x128 tile, 256 threads, 8x8 per thread.

template <int MODE>
__global__ __launch_bounds__(256) void gemm_fused(
    const float* __restrict__ agg, const float* __restrict__ h,
    const float* __restrict__ W, const float* __restrict__ bias,
    float* __restrict__ outf, unsigned* __restrict__ outp, int N)
{
    constexpr int KTOT = MODE ? 128 : 256;
    const int tile = blockIdx.x * 128;
    const int t  = threadIdx.x;
    const int ox = t & 15;          // outs  ox*8 .. +7
    const int ny = t >> 4;          // nodes ny*8 .. +7
    __shared__ float Xs[32][132];
    __shared__ float Ws[32][132];

    float acc[8][8];
    #pragma unroll
    for (int j = 0; j < 8; ++j)
        #pragma unroll
        for (int i = 0; i < 8; ++i) acc[j][i] = 0.0f;

    for (int k0 = 0; k0 < KTOT; k0 += 32) {
        // stage X: 128 rows x 32 k
        {
            const float* __restrict__ srcp = (MODE == 1 || k0 >= 128) ? h : agg;
            const int kk = k0 & 127;
            const int kloc = (t & 7) * 4;
            #pragma unroll
            for (int p = 0; p < 4; ++p) {
                int n = (t >> 3) + p * 32;
                int v = tile + n;
                float4 val = make_float4(0.f, 0.f, 0.f, 0.f);
                if (v < N) val = *(const float4*)&srcp[(size_t)v * 128 + kk + kloc];
                Xs[kloc + 0][n] = val.x; Xs[kloc + 1][n] = val.y;
                Xs[kloc + 2][n] = val.z; Xs[kloc + 3][n] = val.w;
            }
        }
        // stage W (column-XOR swizzled to spread ds_read banks)
        {
            const int kloc = (t & 7) * 4;
            #pragma unroll
            for (int p = 0; p < 4; ++p) {
                int o = (t >> 3) + p * 32;
                float4 wv;
                if (MODE == 0) wv = *(const float4*)&W[(size_t)o * 256 + k0 + kloc];
                else wv = (o < 64) ? *(const float4*)&W[(size_t)o * 256 + k0 + kloc]
                                   : *(const float4*)&W[(size_t)(o - 64) * 256 + 128 + k0 + kloc];
                int op = o ^ (((o >> 5) & 1) * 4);
                Ws[kloc + 0][op] = wv.x; Ws[kloc + 1][op] = wv.y;
                Ws[kloc + 2][op] = wv.z; Ws[kloc + 3][op] = wv.w;
            }
        }
        __syncthreads();

        const int sw = ((ox >> 2) & 1) * 4;
        #pragma unroll
        for (int kk = 0; kk < 32; ++kk) {
            float4 xa = *(const float4*)&Xs[kk][ny * 8];
            float4 xb = *(const float4*)&Xs[kk][ny * 8 + 4];
            float4 wA = *(const float4*)&Ws[kk][ox * 8 + sw];        // logical outs 8ox..+3
            float4 wB = *(const float4*)&Ws[kk][ox * 8 + 4 - sw];    // logical outs 8ox+4..+7
            float xf[8] = {xa.x, xa.y, xa.z, xa.w, xb.x, xb.y, xb.z, xb.w};
            float wf[8] = {wA.x, wA.y, wA.z, wA.w, wB.x, wB.y, wB.z, wB.w};
            #pragma unroll
            for (int j = 0; j < 8; ++j)
                #pragma unroll
                for (int i = 0; i < 8; ++i)
                    acc[j][i] = fmaf(xf[j], wf[i], acc[j][i]);
        }
        __syncthreads();
    }

    // epilogue
    #pragma unroll
    for (int j = 0; j < 8; ++j) {
        int v = tile + ny * 8 + j;
        if (v >= N) continue;
        if (MODE == 0) {
            float r[8];
            #pragma unroll
            for (int i = 0; i < 8; ++i) r[i] = fmaxf(acc[j][i] + bias[ox * 8 + i], 0.0f);
            *(float4*)&outf[(size_t)v * 128 + ox * 8]     = make_float4(r[0], r[1], r[2], r[3]);
            *(float4*)&outf[(size_t)v * 128 + ox * 8 + 4] = make_float4(r[4], r[5], r[6], r[7]);
            uint4 pk;
            pk.x = pack2_bf16(r[0], r[1]); pk.y = pack2_bf16(r[2], r[3]);
            pk.z = pack2_bf16(r[4], r[5]); pk.w = pack2_bf16(r[6], r[7]);
            *(uint4*)&outp[(size_t)v * 64 + ox * 4] = pk;
        } else {
            if (ox < 8) {                       // p -> packed bf16, no bias/relu
                uint4 pk;
                pk.x = pack2_bf16(acc[j][0], acc[j][1]);
                pk.y = pack2_bf16(acc[j][2], acc[j][3]);
                pk.z = pack2_bf16(acc[j][4], acc[j][5]);
                pk.w = pack2_bf16(acc[j][6], acc[j][7]);
                *(uint4*)&outp[(size_t)v * 32 + ox * 4] = pk;
            } else {                            // q -> f32 + bias, no relu
                float r[8];
                #pragma unroll
                for (int i = 0; i < 8; ++i) r[i] = acc[j][i] + bias[(ox - 8) * 8 + i];
                *(float4*)&outf[(size_t)v * 64 + (ox - 8) * 8]     = make_float4(r[0], r[1], r[2], r[3]);
                *(float4*)&outf[(size_t)v * 64 + (ox - 8) * 8 + 4] = make_float4(r[4], r[5], r[6], r[7]);
            }
        }
    }
}

// ---------------- launch ----------------

extern "C" void kernel_launch(void* const* d_in, const int* in_sizes, int n_in,
                              void* d_out, int out_size, void* d_ws, size_t ws_size,
                              hipStream_t stream) {
    const float* n_feat = (const float*)d_in[0];
    const float* ew     = (const float*)d_in[1];
    const int*   src    = (const int*)d_in[2];
    const int*   dst    = (const int*)d_in[3];
    const float* W1 = (const float*)d_in[4];
    const float* b1 = (const float*)d_in[5];
    const float* W2 = (const float*)d_in[6];
    const float* b2 = (const float*)d_in[7];
    const float* W3 = (const float*)d_in[8];
    const float* b3 = (const float*)d_in[9];

    const int N = NN, E = NE;

    uint8_t* w = (uint8_t*)d_ws;
    size_t o = 0;
    auto carve = [&](size_t bytes) { uint8_t* p = w + o; o += (bytes + 255) & ~(size_t)255; return p; };
    unsigned* cnt    = (unsigned*)carve((size_t)N * 4);
    unsigned* off    = (unsigned*)carve((size_t)(N + 1) * 4);
    float*    invdeg = (float*)   carve((size_t)N * 4);
    unsigned long long* edges = (unsigned long long*)carve((size_t)E * 8);
    float*    AGG    = (float*)   carve((size_t)N * 128 * 4);   // also q (first N*64 floats)
    float*    H      = (float*)   carve((size_t)N * 128 * 4);
    unsigned* PK     = (unsigned*)carve((size_t)N * 64 * 4);    // packed bf16 rows / p2

    float* OUT = (float*)d_out;

    // CSR build + packed edge stream
    hipMemsetAsync(cnt, 0, (size_t)N * 4, stream);
    deg_count<<<(E + 255) / 256, 256, 0, stream>>>(dst, cnt, E);
    scan_offsets<<<1, 1024, 0, stream>>>(cnt, off, invdeg, N);
    hipMemsetAsync(cnt, 0, (size_t)N * 4, stream);
    fill_edges<<<(E + 255) / 256, 256, 0, stream>>>(dst, src, ew, cnt, off, edges, E);

    const int gemm_grid = (N + 127) / 128;

    // layer 1
    pack_rows<<<(N * 64 + 255) / 256, 256, 0, stream>>>(n_feat, PK, N * 64);
    aggregate_b<<<N / 4, 256, 0, stream>>>(PK, edges, off, invdeg, AGG);
    gemm_fused<0><<<gemm_grid, 256, 0, stream>>>(AGG, n_feat, W1, b1, H, PK, N);

    // layer 2 (H in-place; PK refreshed with packed h2 -- overwritten later by p2)
    aggregate_b<<<N / 4, 256, 0, stream>>>(PK, edges, off, invdeg, AGG);
    gemm_fused<0><<<gemm_grid, 256, 0, stream>>>(AGG, H, W2, b2, H, PK, N);

    // layer 3: p|q gemm, then fused aggregate+add+relu
    float* Q = AGG;   // [N][64] f32
    gemm_fused<1><<<gemm_grid, 256, 0, stream>>>(H, H, W3, b3, Q, PK, N);
    aggregate64_fused<<<N / 8, 256, 0, stream>>>(PK, edges, off, invdeg, Q, OUT);
}

// Round 4
// 461.653 us; speedup vs baseline: 3.6086x; 1.3466x over previous
//
#include <hip/hip_runtime.h>

#define NN 50000
#define NE 1600000

// ---------------- helpers ----------------

__device__ __forceinline__ unsigned pack2_bf16(float x, float y) {
    unsigned ux = __float_as_uint(x), uy = __float_as_uint(y);
    ux = (ux + 0x7fffu + ((ux >> 16) & 1u)) >> 16;          // RTNE
    uy = (uy + 0x7fffu + ((uy >> 16) & 1u)) >> 16;
    return (uy << 16) | (ux & 0xffffu);
}

// ---------------- CSR build ----------------

__global__ void deg_count(const int* __restrict__ dst, unsigned* __restrict__ cnt, int E) {
    int e = blockIdx.x * blockDim.x + threadIdx.x;
    if (e < E) atomicAdd(&cnt[dst[e]], 1u);
}

// phase 1: per-block (1024) exclusive scan; also inv_deg
__global__ __launch_bounds__(1024) void scan_local(const unsigned* __restrict__ cnt,
                                                   unsigned* __restrict__ off,
                                                   float* __restrict__ inv_deg,
                                                   unsigned* __restrict__ bsum, int N) {
    __shared__ unsigned wsum[16];
    const int i = blockIdx.x * 1024 + threadIdx.x;
    const int lane = threadIdx.x & 63;
    const int wid  = threadIdx.x >> 6;
    unsigned v = (i < N) ? cnt[i] : 0u;
    unsigned x = v;
    #pragma unroll
    for (int s = 1; s < 64; s <<= 1) {
        unsigned t = __shfl_up(x, s, 64);
        if (lane >= s) x += t;
    }
    if (lane == 63) wsum[wid] = x;
    __syncthreads();
    if (wid == 0 && lane < 16) {
        unsigned y = wsum[lane];
        #pragma unroll
        for (int s = 1; s < 16; s <<= 1) {
            unsigned t = __shfl_up(y, s, 64);
            if (lane >= s) y += t;
        }
        wsum[lane] = y;
    }
    __syncthreads();
    unsigned incl = x + ((wid > 0) ? wsum[wid - 1] : 0u);
    if (i < N) {
        off[i] = incl - v;                       // block-local exclusive
        inv_deg[i] = v ? 1.0f / (float)v : 0.0f;
    }
    if (threadIdx.x == 1023) bsum[blockIdx.x] = incl;
}

// phase 2: one wave scans block sums -> exclusive prefixes; writes off[N]=E
__global__ void scan_sums(unsigned* __restrict__ bsum, unsigned* __restrict__ off,
                          int nb, int N) {
    const int t = threadIdx.x;
    unsigned v = (t < nb) ? bsum[t] : 0u;
    unsigned x = v;
    #pragma unroll
    for (int s = 1; s < 64; s <<= 1) {
        unsigned tt = __shfl_up(x, s, 64);
        if (t >= s) x += tt;
    }
    if (t < nb) bsum[t] = x - v;                 // exclusive
    if (t == nb - 1) off[N] = x;                 // total
}

// phase 3: add block prefix
__global__ __launch_bounds__(1024) void scan_add(unsigned* __restrict__ off,
                                                 const unsigned* __restrict__ bsum, int N) {
    int i = blockIdx.x * 1024 + threadIdx.x;
    if (i < N) off[i] += bsum[blockIdx.x];
}

// write dst-sorted packed edge stream: (w_bits<<32 | src)
__global__ void fill_edges(const int* __restrict__ dst, const int* __restrict__ src,
                           const float* __restrict__ ew,
                           unsigned* __restrict__ cursor, const unsigned* __restrict__ off,
                           unsigned long long* __restrict__ edges, int E) {
    int e = blockIdx.x * blockDim.x + threadIdx.x;
    if (e < E) {
        int d = dst[e];
        unsigned p = atomicAdd(&cursor[d], 1u);
        unsigned long long packed =
            ((unsigned long long)__float_as_uint(ew[e]) << 32) | (unsigned)(src[e]);
        edges[off[d] + p] = packed;
    }
}

// ---------------- fused GEMM: P = X@Wa^T (bf16 pack), Q = X@Wh^T + b (f32) ----------
// X [N][128] f32.  W [OUTH][256]: cols 0..127 -> Wa, cols 128..255 -> Wh.
// Output cols (global o' = blockIdx.y*128 + local): o' < OUTH -> P col o',
// else Q col o'-OUTH. 128x128 tile, 256 thr, 8x8 per thread.

template <int OUTH>     // 128 (layers 1/2) or 64 (layer 3)
__global__ __launch_bounds__(256) void gemm_pq(
    const float* __restrict__ X, const float* __restrict__ W,
    const float* __restrict__ bias,
    unsigned* __restrict__ Pout,        // [N][OUTH/2] u32 (bf16x2)
    float* __restrict__ Qout,           // [N][OUTH] f32
    int N)
{
    const int tile = blockIdx.x * 128;
    const int colbase = blockIdx.y * 128;
    const int t  = threadIdx.x;
    const int ox = t & 15;
    const int ny = t >> 4;
    __shared__ float Xs[32][132];
    __shared__ float Ws[32][132];

    float acc[8][8];
    #pragma unroll
    for (int j = 0; j < 8; ++j)
        #pragma unroll
        for (int i = 0; i < 8; ++i) acc[j][i] = 0.0f;

    for (int k0 = 0; k0 < 128; k0 += 32) {
        const int kloc = (t & 7) * 4;
        // stage X: 128 rows x 32 k
        #pragma unroll
        for (int p = 0; p < 4; ++p) {
            int n = (t >> 3) + p * 32;
            int v = tile + n;
            float4 val = make_float4(0.f, 0.f, 0.f, 0.f);
            if (v < N) val = *(const float4*)&X[(size_t)v * 128 + k0 + kloc];
            Xs[kloc + 0][n] = val.x; Xs[kloc + 1][n] = val.y;
            Xs[kloc + 2][n] = val.z; Xs[kloc + 3][n] = val.w;
        }
        // stage W (swizzled)
        #pragma unroll
        for (int p = 0; p < 4; ++p) {
            int o = (t >> 3) + p * 32;
            int oG = colbase + o;
            int is_q = (oG >= OUTH);
            int wr = is_q ? (oG - OUTH) : oG;
            float4 wv = *(const float4*)&W[(size_t)wr * 256 + (is_q ? 128 : 0) + k0 + kloc];
            int op = o ^ (((o >> 5) & 1) * 4);
            Ws[kloc + 0][op] = wv.x; Ws[kloc + 1][op] = wv.y;
            Ws[kloc + 2][op] = wv.z; Ws[kloc + 3][op] = wv.w;
        }
        __syncthreads();

        const int sw = ((ox >> 2) & 1) * 4;
        #pragma unroll
        for (int kk = 0; kk < 32; ++kk) {
            float4 xa = *(const float4*)&Xs[kk][ny * 8];
            float4 xb = *(const float4*)&Xs[kk][ny * 8 + 4];
            float4 wA = *(const float4*)&Ws[kk][ox * 8 + sw];
            float4 wB = *(const float4*)&Ws[kk][ox * 8 + 4 - sw];
            float xf[8] = {xa.x, xa.y, xa.z, xa.w, xb.x, xb.y, xb.z, xb.w};
            float wf[8] = {wA.x, wA.y, wA.z, wA.w, wB.x, wB.y, wB.z, wB.w};
            #pragma unroll
            for (int j = 0; j < 8; ++j)
                #pragma unroll
                for (int i = 0; i < 8; ++i)
                    acc[j][i] = fmaf(xf[j], wf[i], acc[j][i]);
        }
        __syncthreads();
    }

    const int oG0 = colbase + ox * 8;
    #pragma unroll
    for (int j = 0; j < 8; ++j) {
        int v = tile + ny * 8 + j;
        if (v >= N) continue;
        if (oG0 < OUTH) {                       // P region: pack bf16 pairs
            uint4 pk;
            pk.x = pack2_bf16(acc[j][0], acc[j][1]);
            pk.y = pack2_bf16(acc[j][2], acc[j][3]);
            pk.z = pack2_bf16(acc[j][4], acc[j][5]);
            pk.w = pack2_bf16(acc[j][6], acc[j][7]);
            *(uint4*)&Pout[(size_t)v * (OUTH / 2) + (oG0 >> 1)] = pk;
        } else {                                // Q region: + bias, NO relu
            int qc = oG0 - OUTH;
            float4 r0, r1;
            r0.x = acc[j][0] + bias[qc + 0]; r0.y = acc[j][1] + bias[qc + 1];
            r0.z = acc[j][2] + bias[qc + 2]; r0.w = acc[j][3] + bias[qc + 3];
            r1.x = acc[j][4] + bias[qc + 4]; r1.y = acc[j][5] + bias[qc + 5];
            r1.z = acc[j][6] + bias[qc + 6]; r1.w = acc[j][7] + bias[qc + 7];
            *(float4*)&Qout[(size_t)v * OUTH + qc]     = r0;
            *(float4*)&Qout[(size_t)v * OUTH + qc + 4] = r1;
        }
    }
}

// ---------------- fused aggregate: out = relu(mean_agg(P) + Q) ----------------
// LPR lanes per row (16 -> DIM=128, 8 -> DIM=64). Wave per node; each wave-load
// gathers G=64/LPR edges' rows (dwordx4/lane = 1KB/wave). Edge records read
// per-group (shared address -> broadcast). Cross-group combine via shfl_xor.

#define AGG_STEP(ED) {                                                          \
    unsigned srcv = (unsigned)(ED);                                             \
    float wv = __uint_as_float((unsigned)((ED) >> 32));                         \
    const uint4 r = *(const uint4*)&P[(size_t)srcv * (LPR * 4) + lr * 4];       \
    a[0] = fmaf(__uint_as_float(r.x << 16),         wv, a[0]);                  \
    a[1] = fmaf(__uint_as_float(r.x & 0xffff0000u), wv, a[1]);                  \
    a[2] = fmaf(__uint_as_float(r.y << 16),         wv, a[2]);                  \
    a[3] = fmaf(__uint_as_float(r.y & 0xffff0000u), wv, a[3]);                  \
    a[4] = fmaf(__uint_as_float(r.z << 16),         wv, a[4]);                  \
    a[5] = fmaf(__uint_as_float(r.z & 0xffff0000u), wv, a[5]);                  \
    a[6] = fmaf(__uint_as_float(r.w << 16),         wv, a[6]);                  \
    a[7] = fmaf(__uint_as_float(r.w & 0xffff0000u), wv, a[7]); }

template <int LPR>
__global__ __launch_bounds__(256) void agg_fused(
    const unsigned* __restrict__ P,                  // [N][LPR*4] u32 (bf16x2)
    const float* __restrict__ Q,                     // [N][DIM]
    const unsigned long long* __restrict__ edges,    // dst-sorted (w<<32|src)
    const unsigned* __restrict__ off, const float* __restrict__ invdeg,
    float* __restrict__ out)                         // [N][DIM]
{
    constexpr int DIM = LPR * 8;
    constexpr int G   = 64 / LPR;                    // edges per wave iteration
    const int node = blockIdx.x * 4 + (threadIdx.x >> 6);
    const int lane = threadIdx.x & 63;
    const int g    = lane / LPR;
    const int lr   = lane % LPR;
    const unsigned s0 = off[node], s1 = off[node + 1];
    const unsigned deg = s1 - s0;
    const float inv = invdeg[node];

    float a[8];
    #pragma unroll
    for (int i = 0; i < 8; ++i) a[i] = 0.f;

    const unsigned long long* __restrict__ ep = edges + s0 + g;
    const unsigned nfull = deg / G;
    #pragma unroll 4
    for (unsigned it = 0; it < nfull; ++it) {
        unsigned long long ed = ep[(size_t)it * G];
        AGG_STEP(ed);
    }
    const unsigned tail = deg - nfull * G;
    if ((unsigned)g < tail) {
        unsigned long long ed = ep[(size_t)nfull * G];
        AGG_STEP(ed);
    }

    // combine groups
    #pragma unroll
    for (int i = 0; i < 8; ++i) {
        a[i] += __shfl_xor(a[i], 32, 64);
        a[i] += __shfl_xor(a[i], 16, 64);
        if (LPR == 8) a[i] += __shfl_xor(a[i], 8, 64);
    }

    if (lane < LPR) {
        float4 q0 = *(const float4*)&Q[(size_t)node * DIM + lr * 8];
        float4 q1 = *(const float4*)&Q[(size_t)node * DIM + lr * 8 + 4];
        float4 o0, o1;
        o0.x = fmaxf(fmaf(a[0], inv, q0.x), 0.f);
        o0.y = fmaxf(fmaf(a[1], inv, q0.y), 0.f);
        o0.z = fmaxf(fmaf(a[2], inv, q0.z), 0.f);
        o0.w = fmaxf(fmaf(a[3], inv, q0.w), 0.f);
        o1.x = fmaxf(fmaf(a[4], inv, q1.x), 0.f);
        o1.y = fmaxf(fmaf(a[5], inv, q1.y), 0.f);
        o1.z = fmaxf(fmaf(a[6], inv, q1.z), 0.f);
        o1.w = fmaxf(fmaf(a[7], inv, q1.w), 0.f);
        *(float4*)&out[(size_t)node * DIM + lr * 8]     = o0;
        *(float4*)&out[(size_t)node * DIM + lr * 8 + 4] = o1;
    }
}

// ---------------- launch ----------------

extern "C" void kernel_launch(void* const* d_in, const int* in_sizes, int n_in,
                              void* d_out, int out_size, void* d_ws, size_t ws_size,
                              hipStream_t stream) {
    const float* n_feat = (const float*)d_in[0];
    const float* ew     = (const float*)d_in[1];
    const int*   src    = (const int*)d_in[2];
    const int*   dst    = (const int*)d_in[3];
    const float* W1 = (const float*)d_in[4];
    const float* b1 = (const float*)d_in[5];
    const float* W2 = (const float*)d_in[6];
    const float* b2 = (const float*)d_in[7];
    const float* W3 = (const float*)d_in[8];
    const float* b3 = (const float*)d_in[9];

    const int N = NN, E = NE;
    const int NB = (N + 1023) / 1024;          // 49 scan blocks

    uint8_t* w = (uint8_t*)d_ws;
    size_t o = 0;
    auto carve = [&](size_t bytes) { uint8_t* p = w + o; o += (bytes + 255) & ~(size_t)255; return p; };
    unsigned* cnt    = (unsigned*)carve((size_t)N * 4);
    unsigned* off    = (unsigned*)carve((size_t)(N + 1) * 4);
    float*    invdeg = (float*)   carve((size_t)N * 4);
    unsigned* bsum   = (unsigned*)carve((size_t)NB * 4);
    unsigned long long* edges = (unsigned long long*)carve((size_t)E * 8);
    float*    H      = (float*)   carve((size_t)N * 128 * 4);
    unsigned* P      = (unsigned*)carve((size_t)N * 64 * 4);
    float*    Q      = (float*)   carve((size_t)N * 128 * 4);

    float* OUT = (float*)d_out;

    // CSR build
    hipMemsetAsync(cnt, 0, (size_t)N * 4, stream);
    deg_count<<<(E + 255) / 256, 256, 0, stream>>>(dst, cnt, E);
    scan_local<<<NB, 1024, 0, stream>>>(cnt, off, invdeg, bsum, N);
    scan_sums<<<1, 64, 0, stream>>>(bsum, off, NB, N);
    scan_add<<<NB, 1024, 0, stream>>>(off, bsum, N);
    hipMemsetAsync(cnt, 0, (size_t)N * 4, stream);
    fill_edges<<<(E + 255) / 256, 256, 0, stream>>>(dst, src, ew, cnt, off, edges, E);

    const int gx = (N + 127) / 128;

    // layer 1: P,Q from n_feat; h1 = relu(mean_agg(P) + Q)
    gemm_pq<128><<<dim3(gx, 2), 256, 0, stream>>>(n_feat, W1, b1, P, Q, N);
    agg_fused<16><<<N / 4, 256, 0, stream>>>(P, Q, edges, off, invdeg, H);

    // layer 2
    gemm_pq<128><<<dim3(gx, 2), 256, 0, stream>>>(H, W2, b2, P, Q, N);
    agg_fused<16><<<N / 4, 256, 0, stream>>>(P, Q, edges, off, invdeg, H);

    // layer 3 (64 dims)
    gemm_pq<64><<<dim3(gx, 1), 256, 0, stream>>>(H, W3, b3, P, Q, N);
    agg_fused<8><<<N / 4, 256, 0, stream>>>(P, Q, edges, off, invdeg, OUT);
}

// Round 5
// 366.355 us; speedup vs baseline: 4.5473x; 1.2601x over previous
//
#include <hip/hip_runtime.h>

#define NN 50000
#define NE 1600000
#define NPART 196        // ceil(NN / 256)
#define PSZ 256

// ---------------- helpers ----------------

__device__ __forceinline__ unsigned pack2_bf16(float x, float y) {
    unsigned ux = __float_as_uint(x), uy = __float_as_uint(y);
    ux = (ux + 0x7fffu + ((ux >> 16) & 1u)) >> 16;          // RTNE
    uy = (uy + 0x7fffu + ((uy >> 16) & 1u)) >> 16;
    return (uy << 16) | (ux & 0xffffu);
}

// ---------------- CSR build: locality-aware counting sort ----------------

// pass A: partition histogram (partition = dst >> 8)
__global__ __launch_bounds__(256) void part_count(const int* __restrict__ dst,
                                                  unsigned* __restrict__ pcount, int E) {
    __shared__ unsigned hist[NPART];
    for (int i = threadIdx.x; i < NPART; i += 256) hist[i] = 0;
    __syncthreads();
    for (int e = blockIdx.x * 256 + threadIdx.x; e < E; e += gridDim.x * 256)
        atomicAdd(&hist[((unsigned)dst[e]) >> 8], 1u);
    __syncthreads();
    for (int i = threadIdx.x; i < NPART; i += 256) {
        unsigned c = hist[i];
        if (c) atomicAdd(&pcount[i], c);
    }
}

// pass B: scan 196 partition counts -> poff[0..NPART]; init pcursor
__global__ void part_scan(const unsigned* __restrict__ pcount,
                          unsigned* __restrict__ poff, unsigned* __restrict__ pcursor) {
    const int t = threadIdx.x;
    const int lane = t & 63, wid = t >> 6;
    __shared__ unsigned wsum[4];
    unsigned v = (t < NPART) ? pcount[t] : 0u;
    unsigned x = v;
    #pragma unroll
    for (int s = 1; s < 64; s <<= 1) {
        unsigned tt = __shfl_up(x, s, 64);
        if (lane >= s) x += tt;
    }
    if (lane == 63) wsum[wid] = x;
    __syncthreads();
    if (t == 0) { unsigned s = 0; for (int k = 0; k < 4; ++k) { unsigned tt = wsum[k]; wsum[k] = s; s += tt; } }
    __syncthreads();
    unsigned excl = x - v + wsum[wid];
    if (t <= NPART) { poff[t] = excl; pcursor[t] = excl; }
}

// pass C: bucket edges into partition regions; dense per-(block,partition) runs.
// record: w(f32)<<32 | dstoff(8)<<16 | src(16)
__global__ __launch_bounds__(512) void bucket_scatter(
    const int* __restrict__ dst, const int* __restrict__ src, const float* __restrict__ ew,
    unsigned* __restrict__ pcursor, unsigned long long* __restrict__ tmp, int E) {
    __shared__ unsigned hist[NPART];
    __shared__ unsigned gbase[NPART];
    const int chunk = blockIdx.x * 8192;
    for (int i = threadIdx.x; i < NPART; i += 512) hist[i] = 0;
    __syncthreads();
    #pragma unroll
    for (int r = 0; r < 16; ++r) {
        int e = chunk + threadIdx.x + r * 512;
        if (e < E) atomicAdd(&hist[((unsigned)dst[e]) >> 8], 1u);
    }
    __syncthreads();
    for (int i = threadIdx.x; i < NPART; i += 512) {
        unsigned c = hist[i];
        gbase[i] = c ? atomicAdd(&pcursor[i], c) : 0u;
        hist[i] = 0;                               // reuse as rank cursor
    }
    __syncthreads();
    #pragma unroll
    for (int r = 0; r < 16; ++r) {
        int e = chunk + threadIdx.x + r * 512;
        if (e < E) {
            unsigned d = (unsigned)dst[e];
            unsigned part = d >> 8;
            unsigned rank = atomicAdd(&hist[part], 1u);
            unsigned long long rec =
                ((unsigned long long)__float_as_uint(ew[e]) << 32)
              | ((unsigned long long)(d & 0xffu) << 16)
              | (unsigned)src[e];
            tmp[gbase[part] + rank] = rec;
        }
    }
}

// pass D: sort within partition (one block per partition); emit final edges,
// off[], invdeg. Final record: w<<32 | src.
__global__ __launch_bounds__(256) void part_sort(
    const unsigned long long* __restrict__ tmp, const unsigned* __restrict__ poff,
    unsigned long long* __restrict__ edges, unsigned* __restrict__ off,
    float* __restrict__ invdeg, int N) {
    __shared__ unsigned hist[PSZ];
    __shared__ unsigned excl[PSZ];
    __shared__ unsigned wsum[4];
    const int b = blockIdx.x;
    const unsigned e0 = poff[b], e1 = poff[b + 1];
    const int t = threadIdx.x;
    hist[t] = 0;
    __syncthreads();
    for (unsigned i = e0 + t; i < e1; i += 256)
        atomicAdd(&hist[(unsigned)(tmp[i] >> 16) & 0xffu], 1u);
    __syncthreads();
    const unsigned v = hist[t];
    const int lane = t & 63, wid = t >> 6;
    unsigned x = v;
    #pragma unroll
    for (int s = 1; s < 64; s <<= 1) {
        unsigned tt = __shfl_up(x, s, 64);
        if (lane >= s) x += tt;
    }
    if (lane == 63) wsum[wid] = x;
    __syncthreads();
    if (t == 0) { unsigned s = 0; for (int k = 0; k < 4; ++k) { unsigned tt = wsum[k]; wsum[k] = s; s += tt; } }
    __syncthreads();
    const unsigned ex = x - v + wsum[wid];
    excl[t] = ex;
    const int node = b * PSZ + t;
    if (node < N) {
        off[node] = e0 + ex;
        invdeg[node] = v ? 1.0f / (float)v : 0.0f;
    }
    if (b == NPART - 1 && t == 0) off[N] = e1;
    hist[t] = 0;                                   // reuse as cursor
    __syncthreads();
    for (unsigned i = e0 + t; i < e1; i += 256) {
        unsigned long long rec = tmp[i];
        unsigned doff = (unsigned)(rec >> 16) & 0xffu;
        unsigned r = atomicAdd(&hist[doff], 1u);
        edges[e0 + excl[doff] + r] = (rec & 0xffffffff00000000ull) | (rec & 0xffffull);
    }
}

// ---------------- fused GEMM: P = X@Wa^T (bf16 pack), Q = X@Wh^T + b (f32) ----------

template <int OUTH>     // 128 (layers 1/2) or 64 (layer 3)
__global__ __launch_bounds__(256) void gemm_pq(
    const float* __restrict__ X, const float* __restrict__ W,
    const float* __restrict__ bias,
    unsigned* __restrict__ Pout,        // [N][OUTH/2] u32 (bf16x2)
    float* __restrict__ Qout,           // [N][OUTH] f32
    int N)
{
    const int tile = blockIdx.x * 128;
    const int colbase = blockIdx.y * 128;
    const int t  = threadIdx.x;
    const int ox = t & 15;
    const int ny = t >> 4;
    __shared__ float Xs[32][132];
    __shared__ float Ws[32][132];

    float acc[8][8];
    #pragma unroll
    for (int j = 0; j < 8; ++j)
        #pragma unroll
        for (int i = 0; i < 8; ++i) acc[j][i] = 0.0f;

    for (int k0 = 0; k0 < 128; k0 += 32) {
        const int kloc = (t & 7) * 4;
        #pragma unroll
        for (int p = 0; p < 4; ++p) {
            int n = (t >> 3) + p * 32;
            int v = tile + n;
            float4 val = make_float4(0.f, 0.f, 0.f, 0.f);
            if (v < N) val = *(const float4*)&X[(size_t)v * 128 + k0 + kloc];
            Xs[kloc + 0][n] = val.x; Xs[kloc + 1][n] = val.y;
            Xs[kloc + 2][n] = val.z; Xs[kloc + 3][n] = val.w;
        }
        #pragma unroll
        for (int p = 0; p < 4; ++p) {
            int o = (t >> 3) + p * 32;
            int oG = colbase + o;
            int is_q = (oG >= OUTH);
            int wr = is_q ? (oG - OUTH) : oG;
            float4 wv = *(const float4*)&W[(size_t)wr * 256 + (is_q ? 128 : 0) + k0 + kloc];
            int op = o ^ (((o >> 5) & 1) * 4);
            Ws[kloc + 0][op] = wv.x; Ws[kloc + 1][op] = wv.y;
            Ws[kloc + 2][op] = wv.z; Ws[kloc + 3][op] = wv.w;
        }
        __syncthreads();

        const int sw = ((ox >> 2) & 1) * 4;
        #pragma unroll
        for (int kk = 0; kk < 32; ++kk) {
            float4 xa = *(const float4*)&Xs[kk][ny * 8];
            float4 xb = *(const float4*)&Xs[kk][ny * 8 + 4];
            float4 wA = *(const float4*)&Ws[kk][ox * 8 + sw];
            float4 wB = *(const float4*)&Ws[kk][ox * 8 + 4 - sw];
            float xf[8] = {xa.x, xa.y, xa.z, xa.w, xb.x, xb.y, xb.z, xb.w};
            float wf[8] = {wA.x, wA.y, wA.z, wA.w, wB.x, wB.y, wB.z, wB.w};
            #pragma unroll
            for (int j = 0; j < 8; ++j)
                #pragma unroll
                for (int i = 0; i < 8; ++i)
                    acc[j][i] = fmaf(xf[j], wf[i], acc[j][i]);
        }
        __syncthreads();
    }

    const int oG0 = colbase + ox * 8;
    #pragma unroll
    for (int j = 0; j < 8; ++j) {
        int v = tile + ny * 8 + j;
        if (v >= N) continue;
        if (oG0 < OUTH) {
            uint4 pk;
            pk.x = pack2_bf16(acc[j][0], acc[j][1]);
            pk.y = pack2_bf16(acc[j][2], acc[j][3]);
            pk.z = pack2_bf16(acc[j][4], acc[j][5]);
            pk.w = pack2_bf16(acc[j][6], acc[j][7]);
            *(uint4*)&Pout[(size_t)v * (OUTH / 2) + (oG0 >> 1)] = pk;
        } else {
            int qc = oG0 - OUTH;
            float4 r0, r1;
            r0.x = acc[j][0] + bias[qc + 0]; r0.y = acc[j][1] + bias[qc + 1];
            r0.z = acc[j][2] + bias[qc + 2]; r0.w = acc[j][3] + bias[qc + 3];
            r1.x = acc[j][4] + bias[qc + 4]; r1.y = acc[j][5] + bias[qc + 5];
            r1.z = acc[j][6] + bias[qc + 6]; r1.w = acc[j][7] + bias[qc + 7];
            *(float4*)&Qout[(size_t)v * OUTH + qc]     = r0;
            *(float4*)&Qout[(size_t)v * OUTH + qc + 4] = r1;
        }
    }
}

// ---------------- fused aggregate: out = relu(mean_agg(P) + Q) ----------------

#define AGG_STEP(ED) {                                                          \
    unsigned srcv = (unsigned)(ED);                                             \
    float wv = __uint_as_float((unsigned)((ED) >> 32));                         \
    const uint4 r = *(const uint4*)&P[(size_t)srcv * (LPR * 4) + lr * 4];       \
    a[0] = fmaf(__uint_as_float(r.x << 16),         wv, a[0]);                  \
    a[1] = fmaf(__uint_as_float(r.x & 0xffff0000u), wv, a[1]);                  \
    a[2] = fmaf(__uint_as_float(r.y << 16),         wv, a[2]);                  \
    a[3] = fmaf(__uint_as_float(r.y & 0xffff0000u), wv, a[3]);                  \
    a[4] = fmaf(__uint_as_float(r.z << 16),         wv, a[4]);                  \
    a[5] = fmaf(__uint_as_float(r.z & 0xffff0000u), wv, a[5]);                  \
    a[6] = fmaf(__uint_as_float(r.w << 16),         wv, a[6]);                  \
    a[7] = fmaf(__uint_as_float(r.w & 0xffff0000u), wv, a[7]); }

template <int LPR>
__global__ __launch_bounds__(256) void agg_fused(
    const unsigned* __restrict__ P,
    const float* __restrict__ Q,
    const unsigned long long* __restrict__ edges,
    const unsigned* __restrict__ off, const float* __restrict__ invdeg,
    float* __restrict__ out)
{
    constexpr int DIM = LPR * 8;
    constexpr int G   = 64 / LPR;
    const int node = blockIdx.x * 4 + (threadIdx.x >> 6);
    const int lane = threadIdx.x & 63;
    const int g    = lane / LPR;
    const int lr   = lane % LPR;
    const unsigned s0 = off[node], s1 = off[node + 1];
    const unsigned deg = s1 - s0;
    const float inv = invdeg[node];

    float a[8];
    #pragma unroll
    for (int i = 0; i < 8; ++i) a[i] = 0.f;

    const unsigned long long* __restrict__ ep = edges + s0 + g;
    const unsigned nfull = deg / G;
    #pragma unroll 4
    for (unsigned it = 0; it < nfull; ++it) {
        unsigned long long ed = ep[(size_t)it * G];
        AGG_STEP(ed);
    }
    const unsigned tail = deg - nfull * G;
    if ((unsigned)g < tail) {
        unsigned long long ed = ep[(size_t)nfull * G];
        AGG_STEP(ed);
    }

    #pragma unroll
    for (int i = 0; i < 8; ++i) {
        a[i] += __shfl_xor(a[i], 32, 64);
        a[i] += __shfl_xor(a[i], 16, 64);
        if (LPR == 8) a[i] += __shfl_xor(a[i], 8, 64);
    }

    if (lane < LPR) {
        float4 q0 = *(const float4*)&Q[(size_t)node * DIM + lr * 8];
        float4 q1 = *(const float4*)&Q[(size_t)node * DIM + lr * 8 + 4];
        float4 o0, o1;
        o0.x = fmaxf(fmaf(a[0], inv, q0.x), 0.f);
        o0.y = fmaxf(fmaf(a[1], inv, q0.y), 0.f);
        o0.z = fmaxf(fmaf(a[2], inv, q0.z), 0.f);
        o0.w = fmaxf(fmaf(a[3], inv, q0.w), 0.f);
        o1.x = fmaxf(fmaf(a[4], inv, q1.x), 0.f);
        o1.y = fmaxf(fmaf(a[5], inv, q1.y), 0.f);
        o1.z = fmaxf(fmaf(a[6], inv, q1.z), 0.f);
        o1.w = fmaxf(fmaf(a[7], inv, q1.w), 0.f);
        *(float4*)&out[(size_t)node * DIM + lr * 8]     = o0;
        *(float4*)&out[(size_t)node * DIM + lr * 8 + 4] = o1;
    }
}

// ---------------- launch ----------------

extern "C" void kernel_launch(void* const* d_in, const int* in_sizes, int n_in,
                              void* d_out, int out_size, void* d_ws, size_t ws_size,
                              hipStream_t stream) {
    const float* n_feat = (const float*)d_in[0];
    const float* ew     = (const float*)d_in[1];
    const int*   src    = (const int*)d_in[2];
    const int*   dst    = (const int*)d_in[3];
    const float* W1 = (const float*)d_in[4];
    const float* b1 = (const float*)d_in[5];
    const float* W2 = (const float*)d_in[6];
    const float* b2 = (const float*)d_in[7];
    const float* W3 = (const float*)d_in[8];
    const float* b3 = (const float*)d_in[9];

    const int N = NN, E = NE;

    uint8_t* w = (uint8_t*)d_ws;
    size_t o = 0;
    auto carve = [&](size_t bytes) { uint8_t* p = w + o; o += (bytes + 255) & ~(size_t)255; return p; };
    unsigned* pcount  = (unsigned*)carve((size_t)NPART * 4);
    unsigned* poff    = (unsigned*)carve((size_t)(NPART + 1) * 4);
    unsigned* pcursor = (unsigned*)carve((size_t)(NPART + 1) * 4);
    unsigned* off     = (unsigned*)carve((size_t)(N + 1) * 4);
    float*    invdeg  = (float*)   carve((size_t)N * 4);
    unsigned long long* edges = (unsigned long long*)carve((size_t)E * 8);
    float*    H       = (float*)   carve((size_t)N * 128 * 4);
    unsigned* P       = (unsigned*)carve((size_t)N * 64 * 4);
    float*    Q       = (float*)   carve((size_t)N * 128 * 4);
    // tmp edge buffer aliases Q: Q is first written by gemm_pq AFTER part_sort.
    unsigned long long* tmp = (unsigned long long*)Q;

    float* OUT = (float*)d_out;

    // CSR build (counting sort, write-locality aware)
    hipMemsetAsync(pcount, 0, (size_t)NPART * 4, stream);
    part_count<<<392, 256, 0, stream>>>(dst, pcount, E);
    part_scan<<<1, 256, 0, stream>>>(pcount, poff, pcursor);
    bucket_scatter<<<(E + 8191) / 8192, 512, 0, stream>>>(dst, src, ew, pcursor, tmp, E);
    part_sort<<<NPART, 256, 0, stream>>>(tmp, poff, edges, off, invdeg, N);

    const int gx = (N + 127) / 128;

    // layer 1
    gemm_pq<128><<<dim3(gx, 2), 256, 0, stream>>>(n_feat, W1, b1, P, Q, N);
    agg_fused<16><<<N / 4, 256, 0, stream>>>(P, Q, edges, off, invdeg, H);

    // layer 2
    gemm_pq<128><<<dim3(gx, 2), 256, 0, stream>>>(H, W2, b2, P, Q, N);
    agg_fused<16><<<N / 4, 256, 0, stream>>>(P, Q, edges, off, invdeg, H);

    // layer 3 (64 dims)
    gemm_pq<64><<<dim3(gx, 1), 256, 0, stream>>>(H, W3, b3, P, Q, N);
    agg_fused<8><<<N / 4, 256, 0, stream>>>(P, Q, edges, off, invdeg, OUT);
}

// Round 6
// 268.444 us; speedup vs baseline: 6.2058x; 1.3647x over previous
//
#include <hip/hip_runtime.h>

#define NN 50000
#define NE 1600000
#define NPART 196        // ceil(NN / 256)
#define PSZ 256

typedef _Float16 f16;
typedef __attribute__((ext_vector_type(8))) _Float16 f16x8;
typedef __attribute__((ext_vector_type(4))) float f32x4;

// ---------------- CSR build: locality-aware counting sort ----------------

__global__ __launch_bounds__(256) void part_count(const int* __restrict__ dst,
                                                  unsigned* __restrict__ pcount, int E) {
    __shared__ unsigned hist[NPART];
    for (int i = threadIdx.x; i < NPART; i += 256) hist[i] = 0;
    __syncthreads();
    for (int e = blockIdx.x * 256 + threadIdx.x; e < E; e += gridDim.x * 256)
        atomicAdd(&hist[((unsigned)dst[e]) >> 8], 1u);
    __syncthreads();
    for (int i = threadIdx.x; i < NPART; i += 256) {
        unsigned c = hist[i];
        if (c) atomicAdd(&pcount[i], c);
    }
}

__global__ void part_scan(const unsigned* __restrict__ pcount,
                          unsigned* __restrict__ poff, unsigned* __restrict__ pcursor) {
    const int t = threadIdx.x;
    const int lane = t & 63, wid = t >> 6;
    __shared__ unsigned wsum[4];
    unsigned v = (t < NPART) ? pcount[t] : 0u;
    unsigned x = v;
    #pragma unroll
    for (int s = 1; s < 64; s <<= 1) {
        unsigned tt = __shfl_up(x, s, 64);
        if (lane >= s) x += tt;
    }
    if (lane == 63) wsum[wid] = x;
    __syncthreads();
    if (t == 0) { unsigned s = 0; for (int k = 0; k < 4; ++k) { unsigned tt = wsum[k]; wsum[k] = s; s += tt; } }
    __syncthreads();
    unsigned excl = x - v + wsum[wid];
    if (t <= NPART) { poff[t] = excl; pcursor[t] = excl; }
}

// record: w(f32)<<32 | dstoff(8)<<16 | src(16)   [src < 65536 since NN=50000]
__global__ __launch_bounds__(512) void bucket_scatter(
    const int* __restrict__ dst, const int* __restrict__ src, const float* __restrict__ ew,
    unsigned* __restrict__ pcursor, unsigned long long* __restrict__ tmp, int E) {
    __shared__ unsigned hist[NPART];
    __shared__ unsigned gbase[NPART];
    const int chunk = blockIdx.x * 8192;
    for (int i = threadIdx.x; i < NPART; i += 512) hist[i] = 0;
    __syncthreads();
    #pragma unroll
    for (int r = 0; r < 16; ++r) {
        int e = chunk + threadIdx.x + r * 512;
        if (e < E) atomicAdd(&hist[((unsigned)dst[e]) >> 8], 1u);
    }
    __syncthreads();
    for (int i = threadIdx.x; i < NPART; i += 512) {
        unsigned c = hist[i];
        gbase[i] = c ? atomicAdd(&pcursor[i], c) : 0u;
        hist[i] = 0;
    }
    __syncthreads();
    #pragma unroll
    for (int r = 0; r < 16; ++r) {
        int e = chunk + threadIdx.x + r * 512;
        if (e < E) {
            unsigned d = (unsigned)dst[e];
            unsigned part = d >> 8;
            unsigned rank = atomicAdd(&hist[part], 1u);
            unsigned long long rec =
                ((unsigned long long)__float_as_uint(ew[e]) << 32)
              | ((unsigned long long)(d & 0xffu) << 16)
              | (unsigned)src[e];
            tmp[gbase[part] + rank] = rec;
        }
    }
}

__global__ __launch_bounds__(256) void part_sort(
    const unsigned long long* __restrict__ tmp, const unsigned* __restrict__ poff,
    unsigned long long* __restrict__ edges, unsigned* __restrict__ off,
    float* __restrict__ invdeg, int N) {
    __shared__ unsigned hist[PSZ];
    __shared__ unsigned excl[PSZ];
    __shared__ unsigned wsum[4];
    const int b = blockIdx.x;
    const unsigned e0 = poff[b], e1 = poff[b + 1];
    const int t = threadIdx.x;
    hist[t] = 0;
    __syncthreads();
    for (unsigned i = e0 + t; i < e1; i += 256)
        atomicAdd(&hist[(unsigned)(tmp[i] >> 16) & 0xffu], 1u);
    __syncthreads();
    const unsigned v = hist[t];
    const int lane = t & 63, wid = t >> 6;
    unsigned x = v;
    #pragma unroll
    for (int s = 1; s < 64; s <<= 1) {
        unsigned tt = __shfl_up(x, s, 64);
        if (lane >= s) x += tt;
    }
    if (lane == 63) wsum[wid] = x;
    __syncthreads();
    if (t == 0) { unsigned s = 0; for (int k = 0; k < 4; ++k) { unsigned tt = wsum[k]; wsum[k] = s; s += tt; } }
    __syncthreads();
    const unsigned ex = x - v + wsum[wid];
    excl[t] = ex;
    const int node = b * PSZ + t;
    if (node < N) {
        off[node] = e0 + ex;
        invdeg[node] = v ? 1.0f / (float)v : 0.0f;
    }
    if (b == NPART - 1 && t == 0) off[N] = e1;
    hist[t] = 0;
    __syncthreads();
    for (unsigned i = e0 + t; i < e1; i += 256) {
        unsigned long long rec = tmp[i];
        unsigned doff = (unsigned)(rec >> 16) & 0xffu;
        unsigned r = atomicAdd(&hist[doff], 1u);
        edges[e0 + excl[doff] + r] = (rec & 0xffffffff00000000ull) | (rec & 0xffffull);
    }
}

// ---------------- pack f32 [N][128] -> f16 [N][128] ----------------

__global__ __launch_bounds__(256) void pack_x(const float* __restrict__ in,
                                              f16* __restrict__ out, int n8) {
    int i = blockIdx.x * 256 + threadIdx.x;
    if (i < n8) {
        float4 a = ((const float4*)in)[i * 2];
        float4 b = ((const float4*)in)[i * 2 + 1];
        f16x8 h;
        h[0] = (f16)a.x; h[1] = (f16)a.y; h[2] = (f16)a.z; h[3] = (f16)a.w;
        h[4] = (f16)b.x; h[5] = (f16)b.y; h[6] = (f16)b.z; h[7] = (f16)b.w;
        ((f16x8*)out)[i] = h;
    }
}

// ---------------- MFMA GEMM: P = X@Wa^T (f16), Q = X@Wh^T + b (f32) ----------
// X [N][128] f16. W [OUTH][256] f32 (cols 0..127 = Wa, 128..255 = Wh).
// Logical cols 0..2*OUTH-1: < OUTH -> P, else Q. Block: 64 rows x 64 cols,
// 256 thr = 4 waves, whole K=128 in LDS, XOR-swizzled (chunk ^= row&7).
// Wave w: rows w*16..+15, 4 col-tiles of 16, 4 k-steps of 32 -> 16 MFMA.

template <int OUTH>     // 128 (layers 1/2) or 64 (layer 3)
__global__ __launch_bounds__(256) void gemm_mfma(
    const f16* __restrict__ X, const float* __restrict__ W,
    const float* __restrict__ bias,
    f16* __restrict__ Pout,             // [N][OUTH]
    float* __restrict__ Qout,           // [N][OUTH]
    int N)
{
    const int tile = blockIdx.x * 64;
    const int colbase = blockIdx.y * 64;
    const int t = threadIdx.x;
    const int lane = t & 63;
    const int wv = t >> 6;

    __shared__ f16 Xs[64 * 128];
    __shared__ f16 Ws[64 * 128];

    // stage X: 64 rows x 128 f16 (16 uint4-chunks/row), swizzled
    #pragma unroll
    for (int i = 0; i < 4; ++i) {
        int row = i * 16 + (t >> 4);
        int chunk = t & 15;
        int v = tile + row;
        uint4 val = make_uint4(0u, 0u, 0u, 0u);
        if (v < N) val = ((const uint4*)(X + (size_t)v * 128))[chunk];
        ((uint4*)Xs)[row * 16 + (chunk ^ (row & 7))] = val;
    }
    // stage W: 64 local cols x 128 f16, cvt f32->f16, swizzled
    const int isq = (colbase >= OUTH);
    #pragma unroll
    for (int i = 0; i < 4; ++i) {
        int row = i * 16 + (t >> 4);            // local col
        int chunk = t & 15;
        int c = colbase + row;
        const float* wsrc = W + (size_t)(isq ? c - OUTH : c) * 256 + (isq ? 128 : 0) + chunk * 8;
        float4 wa = *(const float4*)wsrc;
        float4 wb = *(const float4*)(wsrc + 4);
        f16x8 wh;
        wh[0] = (f16)wa.x; wh[1] = (f16)wa.y; wh[2] = (f16)wa.z; wh[3] = (f16)wa.w;
        wh[4] = (f16)wb.x; wh[5] = (f16)wb.y; wh[6] = (f16)wb.z; wh[7] = (f16)wb.w;
        ((f16x8*)Ws)[row * 16 + (chunk ^ (row & 7))] = wh;
    }
    __syncthreads();

    const int lr = lane & 15;                   // A-row / B-col within 16
    const int kg = lane >> 4;                   // k-group 0..3
    // A fragments: k = kb*32 + kg*8 + 0..7  -> chunk = kb*4 + kg
    f16x8 afrag[4];
    #pragma unroll
    for (int kb = 0; kb < 4; ++kb) {
        int row = wv * 16 + lr;
        afrag[kb] = ((const f16x8*)Xs)[row * 16 + ((kb * 4 + kg) ^ (row & 7))];
    }
    f32x4 acc[4];
    #pragma unroll
    for (int nt = 0; nt < 4; ++nt)
        #pragma unroll
        for (int j = 0; j < 4; ++j) acc[nt][j] = 0.0f;

    #pragma unroll
    for (int nt = 0; nt < 4; ++nt) {
        int col = nt * 16 + lr;
        #pragma unroll
        for (int kb = 0; kb < 4; ++kb) {
            f16x8 bfrag = ((const f16x8*)Ws)[col * 16 + ((kb * 4 + kg) ^ (col & 7))];
            acc[nt] = __builtin_amdgcn_mfma_f32_16x16x32_f16(afrag[kb], bfrag, acc[nt], 0, 0, 0);
        }
    }

    // epilogue: C/D layout col=lane&15, row=(lane>>4)*4+reg
    #pragma unroll
    for (int nt = 0; nt < 4; ++nt) {
        int c = colbase + nt * 16 + lr;
        #pragma unroll
        for (int j = 0; j < 4; ++j) {
            int v = tile + wv * 16 + kg * 4 + j;
            if (v >= N) continue;
            if (!isq) {
                Pout[(size_t)v * OUTH + c] = (f16)acc[nt][j];
            } else {
                int qc = c - OUTH;
                Qout[(size_t)v * OUTH + qc] = acc[nt][j] + bias[qc];
            }
        }
    }
}

// ---------------- fused aggregate: out = relu(mean_agg(P) + Q) ----------------

#define UNPK(u, lo, hi) { union { unsigned uu; f16 hh[2]; } c_; c_.uu = (u); \
                          lo = (float)c_.hh[0]; hi = (float)c_.hh[1]; }

#define AGG_STEP(ED) {                                                          \
    unsigned srcv = (unsigned)(ED);                                             \
    float wvv = __uint_as_float((unsigned)((ED) >> 32));                        \
    const uint4 r = *(const uint4*)(P + (size_t)srcv * (LPR * 8) + lr * 8);     \
    float f0, f1, f2, f3, f4, f5, f6, f7;                                       \
    UNPK(r.x, f0, f1); UNPK(r.y, f2, f3); UNPK(r.z, f4, f5); UNPK(r.w, f6, f7); \
    a[0] = fmaf(f0, wvv, a[0]); a[1] = fmaf(f1, wvv, a[1]);                     \
    a[2] = fmaf(f2, wvv, a[2]); a[3] = fmaf(f3, wvv, a[3]);                     \
    a[4] = fmaf(f4, wvv, a[4]); a[5] = fmaf(f5, wvv, a[5]);                     \
    a[6] = fmaf(f6, wvv, a[6]); a[7] = fmaf(f7, wvv, a[7]); }

template <int LPR, bool F16OUT>     // LPR lanes/row: 16 -> DIM 128, 8 -> DIM 64
__global__ __launch_bounds__(256) void agg_fused(
    const f16* __restrict__ P,                       // [N][DIM] f16
    const float* __restrict__ Q,                     // [N][DIM] f32
    const unsigned long long* __restrict__ edges,
    const unsigned* __restrict__ off, const float* __restrict__ invdeg,
    void* __restrict__ outv)
{
    constexpr int DIM = LPR * 8;
    constexpr int G   = 64 / LPR;
    const int node = blockIdx.x * 4 + (threadIdx.x >> 6);
    const int lane = threadIdx.x & 63;
    const int g    = lane / LPR;
    const int lr   = lane % LPR;
    const unsigned s0 = off[node], s1 = off[node + 1];
    const unsigned deg = s1 - s0;
    const float inv = invdeg[node];

    float a[8];
    #pragma unroll
    for (int i = 0; i < 8; ++i) a[i] = 0.f;

    const unsigned long long* __restrict__ ep = edges + s0 + g;
    const unsigned nfull = deg / G;
    #pragma unroll 4
    for (unsigned it = 0; it < nfull; ++it) {
        unsigned long long ed = ep[(size_t)it * G];
        AGG_STEP(ed);
    }
    const unsigned tail = deg - nfull * G;
    if ((unsigned)g < tail) {
        unsigned long long ed = ep[(size_t)nfull * G];
        AGG_STEP(ed);
    }

    #pragma unroll
    for (int i = 0; i < 8; ++i) {
        a[i] += __shfl_xor(a[i], 32, 64);
        a[i] += __shfl_xor(a[i], 16, 64);
        if (LPR == 8) a[i] += __shfl_xor(a[i], 8, 64);
    }

    if (lane < LPR) {
        float4 q0 = *(const float4*)&Q[(size_t)node * DIM + lr * 8];
        float4 q1 = *(const float4*)&Q[(size_t)node * DIM + lr * 8 + 4];
        float o[8];
        o[0] = fmaxf(fmaf(a[0], inv, q0.x), 0.f);
        o[1] = fmaxf(fmaf(a[1], inv, q0.y), 0.f);
        o[2] = fmaxf(fmaf(a[2], inv, q0.z), 0.f);
        o[3] = fmaxf(fmaf(a[3], inv, q0.w), 0.f);
        o[4] = fmaxf(fmaf(a[4], inv, q1.x), 0.f);
        o[5] = fmaxf(fmaf(a[5], inv, q1.y), 0.f);
        o[6] = fmaxf(fmaf(a[6], inv, q1.z), 0.f);
        o[7] = fmaxf(fmaf(a[7], inv, q1.w), 0.f);
        if (F16OUT) {
            f16x8 h;
            #pragma unroll
            for (int i = 0; i < 8; ++i) h[i] = (f16)o[i];
            ((f16x8*)outv)[(size_t)node * (DIM / 8) + lr] = h;
        } else {
            float* out = (float*)outv;
            *(float4*)&out[(size_t)node * DIM + lr * 8]     = make_float4(o[0], o[1], o[2], o[3]);
            *(float4*)&out[(size_t)node * DIM + lr * 8 + 4] = make_float4(o[4], o[5], o[6], o[7]);
        }
    }
}

// ---------------- launch ----------------

extern "C" void kernel_launch(void* const* d_in, const int* in_sizes, int n_in,
                              void* d_out, int out_size, void* d_ws, size_t ws_size,
                              hipStream_t stream) {
    const float* n_feat = (const float*)d_in[0];
    const float* ew     = (const float*)d_in[1];
    const int*   src    = (const int*)d_in[2];
    const int*   dst    = (const int*)d_in[3];
    const float* W1 = (const float*)d_in[4];
    const float* b1 = (const float*)d_in[5];
    const float* W2 = (const float*)d_in[6];
    const float* b2 = (const float*)d_in[7];
    const float* W3 = (const float*)d_in[8];
    const float* b3 = (const float*)d_in[9];

    const int N = NN, E = NE;

    uint8_t* w = (uint8_t*)d_ws;
    size_t o = 0;
    auto carve = [&](size_t bytes) { uint8_t* p = w + o; o += (bytes + 255) & ~(size_t)255; return p; };
    unsigned* pcount  = (unsigned*)carve((size_t)NPART * 4);
    unsigned* poff    = (unsigned*)carve((size_t)(NPART + 1) * 4);
    unsigned* pcursor = (unsigned*)carve((size_t)(NPART + 1) * 4);
    unsigned* off     = (unsigned*)carve((size_t)(N + 1) * 4);
    float*    invdeg  = (float*)   carve((size_t)N * 4);
    unsigned long long* edges = (unsigned long long*)carve((size_t)E * 8);
    f16*      Xf      = (f16*)     carve((size_t)N * 128 * 2);  // f16 n_feat
    f16*      H       = (f16*)     carve((size_t)N * 128 * 2);  // f16 hidden
    f16*      P       = (f16*)     carve((size_t)N * 128 * 2);
    float*    Q       = (float*)   carve((size_t)N * 128 * 4);
    unsigned long long* tmp = (unsigned long long*)Q;  // Q first written after part_sort

    float* OUT = (float*)d_out;

    // CSR build (counting sort)
    hipMemsetAsync(pcount, 0, (size_t)NPART * 4, stream);
    part_count<<<392, 256, 0, stream>>>(dst, pcount, E);
    part_scan<<<1, 256, 0, stream>>>(pcount, poff, pcursor);
    bucket_scatter<<<(E + 8191) / 8192, 512, 0, stream>>>(dst, src, ew, pcursor, tmp, E);
    part_sort<<<NPART, 256, 0, stream>>>(tmp, poff, edges, off, invdeg, N);

    const int gx = (N + 63) / 64;

    // layer 1
    pack_x<<<(N * 16 + 255) / 256, 256, 0, stream>>>(n_feat, Xf, N * 16);
    gemm_mfma<128><<<dim3(gx, 4), 256, 0, stream>>>(Xf, W1, b1, P, Q, N);
    agg_fused<16, true><<<N / 4, 256, 0, stream>>>(P, Q, edges, off, invdeg, H);

    // layer 2
    gemm_mfma<128><<<dim3(gx, 4), 256, 0, stream>>>(H, W2, b2, P, Q, N);
    agg_fused<16, true><<<N / 4, 256, 0, stream>>>(P, Q, edges, off, invdeg, H);

    // layer 3 (64 dims out)
    gemm_mfma<64><<<dim3(gx, 2), 256, 0, stream>>>(H, W3, b3, P, Q, N);
    agg_fused<8, false><<<N / 4, 256, 0, stream>>>(P, Q, edges, off, invdeg, OUT);
}